// Round 10
// baseline (256.130 us; speedup 1.0000x reference)
//
#include <hip/hip_runtime.h>
#include <stdint.h>

#define F 128
#define NREP 8          // cursor/histogram replicas (contention /8)
#define EPT 8           // edges per thread in histogram/bucket

// native clang vectors (accepted by __builtin_nontemporal_*)
typedef float f32x2 __attribute__((ext_vector_type(2)));
typedef float f32x4 __attribute__((ext_vector_type(4)));

union H4 { f32x2 f2; _Float16 h[4]; };
union HS { _Float16 h; unsigned short u; };

// packed edge record: low16 = src node, high16 = fp16 norm
typedef uint32_t ERec;

// ---- 1. fused: x(fp32)->xh(fp16) + replicated in-degree histogram ----
__global__ void convdeg_kernel(const float* __restrict__ x, _Float16* __restrict__ xh,
                               int total4, const int* __restrict__ col,
                               int* __restrict__ hist, int E, int N) {
    int rep = blockIdx.x & (NREP - 1);
    int i0 = (blockIdx.x * blockDim.x + threadIdx.x) * EPT;
    int* h = hist + (size_t)rep * N;
#pragma unroll
    for (int u = 0; u < EPT; ++u) {
        int e = i0 + u;
        if (e < E) atomicAdd(&h[__builtin_nontemporal_load(&col[e])], 1);
    }
#pragma unroll
    for (int u = 0; u < EPT; ++u) {
        int i = i0 + u;
        if (i < total4) {
            f32x4 v = __builtin_nontemporal_load(&((const f32x4*)x)[i]);
            H4 p;
            p.h[0] = (_Float16)v.x; p.h[1] = (_Float16)v.y;
            p.h[2] = (_Float16)v.z; p.h[3] = (_Float16)v.w;
            ((f32x2*)xh)[i] = p.f2;            // reused by layer 0 -> keep cacheable
        }
    }
}

// ---- 2. fused node-side: deg-sum + dinv + exclusive scan + cursor seed ----
__global__ __launch_bounds__(1024) void nodeproc_kernel(
        const int* __restrict__ hist, float* __restrict__ dinv,
        int* __restrict__ start, int* __restrict__ cursor, int N) {
    __shared__ int wsum[16];
    __shared__ int carry_s;
    int tid = threadIdx.x, lane = tid & 63, wid = tid >> 6;
    if (tid == 0) carry_s = 0;
    __syncthreads();
    for (int base = 0; base < N; base += 1024) {
        int i = base + tid;
        int h[NREP];
        int v = 0;
        if (i < N) {
#pragma unroll
            for (int r = 0; r < NREP; ++r) { h[r] = hist[(size_t)r * N + i]; v += h[r]; }
            int d = v < 1 ? 1 : v;
            dinv[i] = rsqrtf((float)d);
        }
        int inc = v;                              // wave-inclusive scan
        for (int off = 1; off < 64; off <<= 1) {
            int t = __shfl_up(inc, off, 64);
            if (lane >= off) inc += t;
        }
        if (lane == 63) wsum[wid] = inc;
        __syncthreads();
        if (wid == 0) {
            int wv = (lane < 16) ? wsum[lane] : 0;
            for (int off = 1; off < 16; off <<= 1) {
                int t = __shfl_up(wv, off, 64);
                if (lane >= off) wv += t;
            }
            if (lane < 16) wsum[lane] = wv;       // inclusive wave totals
        }
        __syncthreads();
        int carry = carry_s;
        int woff = (wid > 0) ? wsum[wid - 1] : 0;
        if (i < N) {
            int st = carry + woff + inc - v;      // exclusive prefix
            start[i] = st;
            int run = st;
#pragma unroll
            for (int r = 0; r < NREP; ++r) { cursor[(size_t)r * N + i] = run; run += h[r]; }
        }
        __syncthreads();
        if (tid == 0) carry_s = carry + wsum[15];
        __syncthreads();
    }
    if (tid == 0) start[N] = carry_s;
}

// ---- 3. bucket scatter: packed 4B records, pre-seeded replicated cursors ----
__global__ void bucket_kernel(const int* __restrict__ row, const int* __restrict__ col,
                              const float* __restrict__ dinv,
                              int* __restrict__ cursor, ERec* __restrict__ edges,
                              int E, int N) {
    int rep = blockIdx.x & (NREP - 1);
    int e0 = (blockIdx.x * blockDim.x + threadIdx.x) * EPT;
    int* cur = cursor + (size_t)rep * N;
    int cs[EPT], rs[EPT], pos[EPT];
    float nm[EPT];
#pragma unroll
    for (int u = 0; u < EPT; ++u) {
        int e = e0 + u;
        if (e < E) {
            cs[u] = __builtin_nontemporal_load(&col[e]);
            rs[u] = __builtin_nontemporal_load(&row[e]);
        }
    }
#pragma unroll
    for (int u = 0; u < EPT; ++u) {
        int e = e0 + u;
        if (e < E) {
            nm[u]  = dinv[rs[u]] * dinv[cs[u]];
            pos[u] = atomicAdd(&cur[cs[u]], 1);
        }
    }
#pragma unroll
    for (int u = 0; u < EPT; ++u) {
        int e = e0 + u;
        if (e < E) {
            HS hs; hs.h = (_Float16)nm[u];
            ERec rec = (uint32_t)rs[u] | ((uint32_t)hs.u << 16);
            edges[pos[u]] = rec;               // reused 8x by layers -> cacheable
        }
    }
}

// ---- 4. one layer (fp16): half-wave 8B gathers, 16 load-instrs in flight ----
// half h (32 lanes) handles staged edges j+2u+h; lane li covers halves
// 4*li..4*li+3 (8 B). One wave-instruction = one full 256 B row x 2 edges
// -> 4 cache lines per instr, 16 instrs outstanding = 64 lines MLP/wave.
__global__ __launch_bounds__(256) void layer_kernel(
        const _Float16* __restrict__ cin, _Float16* __restrict__ cout,
        const int* __restrict__ start, const ERec* __restrict__ edges, int N) {
    int node = (blockIdx.x * blockDim.x + threadIdx.x) >> 6;
    int lane = threadIdx.x & 63;
    if (node >= N) return;
    int h  = lane >> 5;        // half 0..1
    int li = lane & 31;        // lane-in-half
    int s = start[node], t = start[node + 1];

    float a[4][4];
#pragma unroll
    for (int u = 0; u < 4; ++u)
#pragma unroll
        for (int c = 0; c < 4; ++c) a[u][c] = 0.f;

    for (int base = s; base < t; base += 64) {
        int cnt = t - base; if (cnt > 64) cnt = 64;
        ERec rec = edges[base + (lane < cnt ? lane : cnt - 1)];   // coalesced staging
        int j = 0;
        for (; j + 32 <= cnt; j += 32) {
#pragma unroll
            for (int u = 0; u < 16; ++u) {
                int idx = j + 2 * u + h;
                uint32_t r_ = (uint32_t)__shfl((int)rec, idx, 64);
                int s_ = (int)(r_ & 0xffffu);
                HS hs; hs.u = (unsigned short)(r_ >> 16);
                float n_ = (float)hs.h;
                H4 v; v.f2 = ((const f32x2*)(cin + (size_t)s_ * F))[li];
#pragma unroll
                for (int c = 0; c < 4; ++c) a[u & 3][c] += n_ * (float)v.h[c];
            }
        }
        for (; j < cnt; j += 2) {
            int idx = j + h;
            int ic  = idx < cnt ? idx : j;
            uint32_t r_ = (uint32_t)__shfl((int)rec, ic, 64);
            int s_ = (int)(r_ & 0xffffu);
            HS hs; hs.u = (unsigned short)(r_ >> 16);
            float n_ = (float)hs.h;
            if (idx >= cnt) n_ = 0.f;
            H4 v; v.f2 = ((const f32x2*)(cin + (size_t)s_ * F))[li];
#pragma unroll
            for (int c = 0; c < 4; ++c) a[0][c] += n_ * (float)v.h[c];
        }
    }
    float r[4];
#pragma unroll
    for (int c = 0; c < 4; ++c) {
        r[c] = (a[0][c] + a[1][c]) + (a[2][c] + a[3][c]);
        r[c] += __shfl_xor(r[c], 32, 64);      // combine halves
    }
    if (h == 0) {
        H4 cvn; cvn.f2 = ((const f32x2*)(cin + (size_t)node * F))[li];
        H4 o;
#pragma unroll
        for (int c = 0; c < 4; ++c) o.h[c] = (_Float16)((float)cvn.h[c] - r[c]);
        ((f32x2*)(cout + (size_t)node * F))[li] = o.f2;   // reused next layer -> cacheable
    }
}

// ---- 5. epilogue: update = sum_l tanh(k_l)*cur_l; h = c*upd+(1-c)*x;
//          out = relu(h @ W^T + b) ----
#define TM 32
#define KC 32
__global__ __launch_bounds__(256) void final_kernel(
        const float* __restrict__ x, const _Float16* __restrict__ curh,
        const float* __restrict__ W, const float* __restrict__ bias,
        const float* __restrict__ kv, const float* __restrict__ wt,
        float* __restrict__ out, int N, int L) {
    __shared__ float hs[TM * F];
    __shared__ float Wl[KC * 129];
    int tid  = threadIdx.x;
    int row0 = blockIdx.x * TM;
    float cst  = 1.f / (1.f + __expf(-wt[0]));
    float cst1 = 1.f - cst;
    float t[16];
    for (int l = 0; l < L; ++l) t[l] = tanhf(kv[l]);
    const size_t NF = (size_t)N * F;

    for (int j = tid; j < TM * 32; j += 256) {
        int r = j >> 5, qd = j & 31;
        int gr = row0 + r;
        f32x4 hv = {0.f, 0.f, 0.f, 0.f};
        if (gr < N) {
            f32x4 xv = __builtin_nontemporal_load(&((const f32x4*)(x + (size_t)gr * F))[qd]);
            float sx = 0.f, sy = 0.f, sz = 0.f, sw = 0.f;
            for (int l = 0; l < L; ++l) {
                H4 u;
                u.f2 = __builtin_nontemporal_load(
                    &((const f32x2*)(curh + (size_t)l * NF + (size_t)gr * F))[qd]);
                sx += t[l] * (float)u.h[0]; sy += t[l] * (float)u.h[1];
                sz += t[l] * (float)u.h[2]; sw += t[l] * (float)u.h[3];
            }
            hv.x = cst * sx + cst1 * xv.x;
            hv.y = cst * sy + cst1 * xv.y;
            hv.z = cst * sz + cst1 * xv.z;
            hv.w = cst * sw + cst1 * xv.w;
        }
        ((f32x4*)hs)[j] = hv;
    }

    int c  = tid & 127;
    int rg = tid >> 7;
    float acc[16];
#pragma unroll
    for (int i = 0; i < 16; ++i) acc[i] = 0.f;
    for (int kc = 0; kc < F; kc += KC) {
        __syncthreads();
        for (int j = tid; j < KC * F; j += 256) {
            int c2 = j >> 5, kk = j & 31;
            Wl[kk * 129 + c2] = W[(size_t)c2 * F + kc + kk];
        }
        __syncthreads();
#pragma unroll 8
        for (int kk = 0; kk < KC; ++kk) {
            float w = Wl[kk * 129 + c];
#pragma unroll
            for (int r = 0; r < 16; ++r)
                acc[r] += hs[(rg * 16 + r) * F + kc + kk] * w;
        }
    }
    float bv = bias[c];
#pragma unroll
    for (int r = 0; r < 16; ++r) {
        int gr = row0 + rg * 16 + r;
        if (gr < N) {
            float v = acc[r] + bv;
            out[(size_t)gr * F + c] = v > 0.f ? v : 0.f;
        }
    }
}

extern "C" void kernel_launch(void* const* d_in, const int* in_sizes, int n_in,
                              void* d_out, int out_size, void* d_ws, size_t ws_size,
                              hipStream_t stream) {
    const float* x   = (const float*)d_in[0];
    const int*   ei  = (const int*)d_in[1];
    const float* kv  = (const float*)d_in[2];
    const float* wt  = (const float*)d_in[3];
    const float* W   = (const float*)d_in[4];
    const float* b   = (const float*)d_in[5];
    float* out = (float*)d_out;

    const int E = in_sizes[1] / 2;
    const int N = in_sizes[0] / F;
    const int L = in_sizes[2];
    const int* row = ei;           // edge_index[0]
    const int* col = ei + E;       // edge_index[1]
    const size_t NF = (size_t)N * F;
    const int total4 = (int)(NF / 4);

    size_t off = 0;
    auto alloc = [&](size_t bytes) {
        void* p = (char*)d_ws + off;
        off += (bytes + 255) & ~(size_t)255;
        return p;
    };
    int*      hist   = (int*)alloc((size_t)NREP * N * 4);
    int*      cursor = (int*)alloc((size_t)NREP * N * 4);
    int*      startp = (int*)alloc((size_t)(N + 1) * 4);
    float*    dinv   = (float*)alloc((size_t)N * 4);
    ERec*     edges  = (ERec*)alloc((size_t)E * sizeof(ERec));
    _Float16* xh     = (_Float16*)alloc(NF * 2);
    _Float16* curh   = (_Float16*)alloc((size_t)L * NF * 2);
    (void)ws_size;

    (void)hipMemsetAsync(hist, 0, (size_t)NREP * N * 4, stream);

    const int work = (E > total4 ? E : total4);
    const int nb_edge = (work + 256 * EPT - 1) / (256 * EPT);   // same geometry for bucket
    convdeg_kernel<<<nb_edge, 256, 0, stream>>>(x, xh, total4, col, hist, E, N);
    nodeproc_kernel<<<1, 1024, 0, stream>>>(hist, dinv, startp, cursor, N);
    bucket_kernel<<<nb_edge, 256, 0, stream>>>(row, col, dinv, cursor, edges, E, N);

    for (int l = 0; l < L; ++l) {
        const _Float16* cin = (l == 0) ? xh : curh + (size_t)(l - 1) * NF;
        _Float16* cout = curh + (size_t)l * NF;
        layer_kernel<<<(N * 64 + 255) / 256, 256, 0, stream>>>(cin, cout, startp, edges, N);
    }

    final_kernel<<<(N + TM - 1) / TM, 256, 0, stream>>>(x, curh, W, b, kv, wt, out, N, L);
}

// Round 11
// 239.201 us; speedup vs baseline: 1.0708x; 1.0708x over previous
//
#include <hip/hip_runtime.h>
#include <stdint.h>

#define F 128
#define NREP 8          // cursor/histogram replicas (contention /8)
#define EPT 8           // edges per thread in histogram/bucket

// native clang vectors (accepted by __builtin_nontemporal_* and packed math)
typedef float f32x2 __attribute__((ext_vector_type(2)));
typedef float f32x4 __attribute__((ext_vector_type(4)));
typedef _Float16 h2 __attribute__((ext_vector_type(2)));

union H4 { f32x2 f2; _Float16 h[4]; };
union H8 { f32x4 f4; h2 p[4]; _Float16 h[8]; };
union HS { _Float16 h; unsigned short u; };

// packed edge record: low16 = src node, high16 = fp16 norm
typedef uint32_t ERec;

// ---- 1. fused: x(fp32)->xh(fp16) + replicated in-degree histogram ----
__global__ void convdeg_kernel(const float* __restrict__ x, _Float16* __restrict__ xh,
                               int total4, const int* __restrict__ col,
                               int* __restrict__ hist, int E, int N) {
    int rep = blockIdx.x & (NREP - 1);
    int i0 = (blockIdx.x * blockDim.x + threadIdx.x) * EPT;
    int* h = hist + (size_t)rep * N;
#pragma unroll
    for (int u = 0; u < EPT; ++u) {
        int e = i0 + u;
        if (e < E) atomicAdd(&h[__builtin_nontemporal_load(&col[e])], 1);
    }
#pragma unroll
    for (int u = 0; u < EPT; ++u) {
        int i = i0 + u;
        if (i < total4) {
            f32x4 v = __builtin_nontemporal_load(&((const f32x4*)x)[i]);
            H4 p;
            p.h[0] = (_Float16)v.x; p.h[1] = (_Float16)v.y;
            p.h[2] = (_Float16)v.z; p.h[3] = (_Float16)v.w;
            ((f32x2*)xh)[i] = p.f2;            // reused by layer 0 -> keep cacheable
        }
    }
}

// ---- 2. fused node-side: deg-sum + dinv + exclusive scan + cursor seed ----
__global__ __launch_bounds__(1024) void nodeproc_kernel(
        const int* __restrict__ hist, float* __restrict__ dinv,
        int* __restrict__ start, int* __restrict__ cursor, int N) {
    __shared__ int wsum[16];
    __shared__ int carry_s;
    int tid = threadIdx.x, lane = tid & 63, wid = tid >> 6;
    if (tid == 0) carry_s = 0;
    __syncthreads();
    for (int base = 0; base < N; base += 1024) {
        int i = base + tid;
        int h[NREP];
        int v = 0;
        if (i < N) {
#pragma unroll
            for (int r = 0; r < NREP; ++r) { h[r] = hist[(size_t)r * N + i]; v += h[r]; }
            int d = v < 1 ? 1 : v;
            dinv[i] = rsqrtf((float)d);
        }
        int inc = v;                              // wave-inclusive scan
        for (int off = 1; off < 64; off <<= 1) {
            int t = __shfl_up(inc, off, 64);
            if (lane >= off) inc += t;
        }
        if (lane == 63) wsum[wid] = inc;
        __syncthreads();
        if (wid == 0) {
            int wv = (lane < 16) ? wsum[lane] : 0;
            for (int off = 1; off < 16; off <<= 1) {
                int t = __shfl_up(wv, off, 64);
                if (lane >= off) wv += t;
            }
            if (lane < 16) wsum[lane] = wv;       // inclusive wave totals
        }
        __syncthreads();
        int carry = carry_s;
        int woff = (wid > 0) ? wsum[wid - 1] : 0;
        if (i < N) {
            int st = carry + woff + inc - v;      // exclusive prefix
            start[i] = st;
            int run = st;
#pragma unroll
            for (int r = 0; r < NREP; ++r) { cursor[(size_t)r * N + i] = run; run += h[r]; }
        }
        __syncthreads();
        if (tid == 0) carry_s = carry + wsum[15];
        __syncthreads();
    }
    if (tid == 0) start[N] = carry_s;
}

// ---- 3. bucket scatter: packed 4B records, pre-seeded replicated cursors ----
__global__ void bucket_kernel(const int* __restrict__ row, const int* __restrict__ col,
                              const float* __restrict__ dinv,
                              int* __restrict__ cursor, ERec* __restrict__ edges,
                              int E, int N) {
    int rep = blockIdx.x & (NREP - 1);
    int e0 = (blockIdx.x * blockDim.x + threadIdx.x) * EPT;
    int* cur = cursor + (size_t)rep * N;
    int cs[EPT], rs[EPT], pos[EPT];
    float nm[EPT];
#pragma unroll
    for (int u = 0; u < EPT; ++u) {
        int e = e0 + u;
        if (e < E) {
            cs[u] = __builtin_nontemporal_load(&col[e]);
            rs[u] = __builtin_nontemporal_load(&row[e]);
        }
    }
#pragma unroll
    for (int u = 0; u < EPT; ++u) {
        int e = e0 + u;
        if (e < E) {
            nm[u]  = dinv[rs[u]] * dinv[cs[u]];
            pos[u] = atomicAdd(&cur[cs[u]], 1);
        }
    }
#pragma unroll
    for (int u = 0; u < EPT; ++u) {
        int e = e0 + u;
        if (e < E) {
            HS hs; hs.h = (_Float16)nm[u];
            ERec rec = (uint32_t)rs[u] | ((uint32_t)hs.u << 16);
            edges[pos[u]] = rec;               // reused 8x by layers -> cacheable
        }
    }
}

// ---- 4. one layer: quarter-wave f32x4 gathers + packed-fp16 MAC ----
// quarter q handles staged edges j+4u+q; lane li covers halves 8*li..8*li+7.
// MAC: 4 v_pk_fma_f16 per edge (vs 8 cvt + 8 fma), fp16 pair-accumulators
// flushed to fp32 every 8 edges to bound rounding error.
__global__ __launch_bounds__(256) void layer_kernel(
        const _Float16* __restrict__ cin, _Float16* __restrict__ cout,
        const int* __restrict__ start, const ERec* __restrict__ edges, int N) {
    int node = (blockIdx.x * blockDim.x + threadIdx.x) >> 6;
    int lane = threadIdx.x & 63;
    if (node >= N) return;
    int q  = lane >> 4;        // quarter 0..3
    int li = lane & 15;        // lane-in-quarter
    int s = start[node], t = start[node + 1];

    float a[8];
#pragma unroll
    for (int i = 0; i < 8; ++i) a[i] = 0.f;

    for (int base = s; base < t; base += 64) {
        int cnt = t - base; if (cnt > 64) cnt = 64;
        ERec rec = edges[base + (lane < cnt ? lane : cnt - 1)];   // coalesced staging
        int j = 0;
        for (; j + 32 <= cnt; j += 32) {
            h2 hacc[4];
#pragma unroll
            for (int c = 0; c < 4; ++c) hacc[c] = (h2)(_Float16)0.f;
#pragma unroll
            for (int u = 0; u < 8; ++u) {          // 8 edges per quarter
                int idx = j + 4 * u + q;
                uint32_t r_ = (uint32_t)__shfl((int)rec, idx, 64);
                int s_ = (int)(r_ & 0xffffu);
                HS hs; hs.u = (unsigned short)(r_ >> 16);
                h2 n2; n2[0] = hs.h; n2[1] = hs.h;
                H8 v; v.f4 = ((const f32x4*)(cin + (size_t)s_ * F))[li];
#pragma unroll
                for (int c = 0; c < 4; ++c) hacc[c] += n2 * v.p[c];  // v_pk_fma_f16
            }
#pragma unroll
            for (int c = 0; c < 4; ++c) {          // flush to fp32
                a[2 * c]     += (float)hacc[c][0];
                a[2 * c + 1] += (float)hacc[c][1];
            }
        }
        for (; j < cnt; j += 4) {                  // remainder: fp32 path
            int idx = j + q;
            int ic  = idx < cnt ? idx : j;
            uint32_t r_ = (uint32_t)__shfl((int)rec, ic, 64);
            int s_ = (int)(r_ & 0xffffu);
            HS hs; hs.u = (unsigned short)(r_ >> 16);
            float n_ = (float)hs.h;
            if (idx >= cnt) n_ = 0.f;
            H8 v; v.f4 = ((const f32x4*)(cin + (size_t)s_ * F))[li];
#pragma unroll
            for (int i = 0; i < 8; ++i) a[i] += n_ * (float)v.h[i];
        }
    }
    // combine quarters (lanes li, li+16, li+32, li+48 hold same columns)
#pragma unroll
    for (int i = 0; i < 8; ++i) {
        a[i] += __shfl_xor(a[i], 16, 64);
        a[i] += __shfl_xor(a[i], 32, 64);
    }
    if (q == 0) {
        H8 c; c.f4 = ((const f32x4*)(cin + (size_t)node * F))[li];
        H8 o;
#pragma unroll
        for (int i = 0; i < 8; ++i) o.h[i] = (_Float16)((float)c.h[i] - a[i]);
        ((f32x4*)(cout + (size_t)node * F))[li] = o.f4;   // reused next layer -> cacheable
    }
}

// ---- 5. epilogue: update = sum_l tanh(k_l)*cur_l; h = c*upd+(1-c)*x;
//          out = relu(h @ W^T + b) ----
#define TM 32
#define KC 32
__global__ __launch_bounds__(256) void final_kernel(
        const float* __restrict__ x, const _Float16* __restrict__ curh,
        const float* __restrict__ W, const float* __restrict__ bias,
        const float* __restrict__ kv, const float* __restrict__ wt,
        float* __restrict__ out, int N, int L) {
    __shared__ float hs[TM * F];
    __shared__ float Wl[KC * 129];
    int tid  = threadIdx.x;
    int row0 = blockIdx.x * TM;
    float cst  = 1.f / (1.f + __expf(-wt[0]));
    float cst1 = 1.f - cst;
    float t[16];
    for (int l = 0; l < L; ++l) t[l] = tanhf(kv[l]);
    const size_t NF = (size_t)N * F;

    for (int j = tid; j < TM * 32; j += 256) {
        int r = j >> 5, qd = j & 31;
        int gr = row0 + r;
        f32x4 hv = {0.f, 0.f, 0.f, 0.f};
        if (gr < N) {
            f32x4 xv = __builtin_nontemporal_load(&((const f32x4*)(x + (size_t)gr * F))[qd]);
            float sx = 0.f, sy = 0.f, sz = 0.f, sw = 0.f;
            for (int l = 0; l < L; ++l) {
                H4 u;
                u.f2 = ((const f32x2*)(curh + (size_t)l * NF + (size_t)gr * F))[qd];
                sx += t[l] * (float)u.h[0]; sy += t[l] * (float)u.h[1];
                sz += t[l] * (float)u.h[2]; sw += t[l] * (float)u.h[3];
            }
            hv.x = cst * sx + cst1 * xv.x;
            hv.y = cst * sy + cst1 * xv.y;
            hv.z = cst * sz + cst1 * xv.z;
            hv.w = cst * sw + cst1 * xv.w;
        }
        ((f32x4*)hs)[j] = hv;
    }

    int c  = tid & 127;
    int rg = tid >> 7;
    float acc[16];
#pragma unroll
    for (int i = 0; i < 16; ++i) acc[i] = 0.f;
    for (int kc = 0; kc < F; kc += KC) {
        __syncthreads();
        for (int j = tid; j < KC * F; j += 256) {
            int c2 = j >> 5, kk = j & 31;
            Wl[kk * 129 + c2] = W[(size_t)c2 * F + kc + kk];
        }
        __syncthreads();
#pragma unroll 8
        for (int kk = 0; kk < KC; ++kk) {
            float w = Wl[kk * 129 + c];
#pragma unroll
            for (int r = 0; r < 16; ++r)
                acc[r] += hs[(rg * 16 + r) * F + kc + kk] * w;
        }
    }
    float bv = bias[c];
#pragma unroll
    for (int r = 0; r < 16; ++r) {
        int gr = row0 + rg * 16 + r;
        if (gr < N) {
            float v = acc[r] + bv;
            out[(size_t)gr * F + c] = v > 0.f ? v : 0.f;
        }
    }
}

extern "C" void kernel_launch(void* const* d_in, const int* in_sizes, int n_in,
                              void* d_out, int out_size, void* d_ws, size_t ws_size,
                              hipStream_t stream) {
    const float* x   = (const float*)d_in[0];
    const int*   ei  = (const int*)d_in[1];
    const float* kv  = (const float*)d_in[2];
    const float* wt  = (const float*)d_in[3];
    const float* W   = (const float*)d_in[4];
    const float* b   = (const float*)d_in[5];
    float* out = (float*)d_out;

    const int E = in_sizes[1] / 2;
    const int N = in_sizes[0] / F;
    const int L = in_sizes[2];
    const int* row = ei;           // edge_index[0]
    const int* col = ei + E;       // edge_index[1]
    const size_t NF = (size_t)N * F;
    const int total4 = (int)(NF / 4);

    size_t off = 0;
    auto alloc = [&](size_t bytes) {
        void* p = (char*)d_ws + off;
        off += (bytes + 255) & ~(size_t)255;
        return p;
    };
    int*      hist   = (int*)alloc((size_t)NREP * N * 4);
    int*      cursor = (int*)alloc((size_t)NREP * N * 4);
    int*      startp = (int*)alloc((size_t)(N + 1) * 4);
    float*    dinv   = (float*)alloc((size_t)N * 4);
    ERec*     edges  = (ERec*)alloc((size_t)E * sizeof(ERec));
    _Float16* xh     = (_Float16*)alloc(NF * 2);
    _Float16* curh   = (_Float16*)alloc((size_t)L * NF * 2);
    (void)ws_size;

    (void)hipMemsetAsync(hist, 0, (size_t)NREP * N * 4, stream);

    const int work = (E > total4 ? E : total4);
    const int nb_edge = (work + 256 * EPT - 1) / (256 * EPT);   // same geometry for bucket
    convdeg_kernel<<<nb_edge, 256, 0, stream>>>(x, xh, total4, col, hist, E, N);
    nodeproc_kernel<<<1, 1024, 0, stream>>>(hist, dinv, startp, cursor, N);
    bucket_kernel<<<nb_edge, 256, 0, stream>>>(row, col, dinv, cursor, edges, E, N);

    for (int l = 0; l < L; ++l) {
        const _Float16* cin = (l == 0) ? xh : curh + (size_t)(l - 1) * NF;
        _Float16* cout = curh + (size_t)l * NF;
        layer_kernel<<<(N * 64 + 255) / 256, 256, 0, stream>>>(cin, cout, startp, edges, N);
    }

    final_kernel<<<(N + TM - 1) / TM, 256, 0, stream>>>(x, curh, W, b, kv, wt, out, N, L);
}

// Round 12
// 236.235 us; speedup vs baseline: 1.0842x; 1.0126x over previous
//
#include <hip/hip_runtime.h>
#include <stdint.h>

#define F 128
#define NREP 8          // cursor/histogram replicas (contention /8)
#define EPT 8           // edges per thread in histogram/bucket

// native clang vectors (accepted by __builtin_nontemporal_* and packed math)
typedef float f32x2 __attribute__((ext_vector_type(2)));
typedef float f32x4 __attribute__((ext_vector_type(4)));
typedef _Float16 h2 __attribute__((ext_vector_type(2)));

union H4 { f32x2 f2; _Float16 h[4]; };
union H8 { f32x4 f4; h2 p[4]; _Float16 h[8]; };
union HS { _Float16 h; unsigned short u; };

// packed edge record: low16 = src node, high16 = fp16 norm
typedef uint32_t ERec;

// ---- 1. fused: x(fp32)->xh(fp16) + replicated in-degree histogram ----
__global__ void convdeg_kernel(const float* __restrict__ x, _Float16* __restrict__ xh,
                               int total4, const int* __restrict__ col,
                               int* __restrict__ hist, int E, int N) {
    int rep = blockIdx.x & (NREP - 1);
    int i0 = (blockIdx.x * blockDim.x + threadIdx.x) * EPT;
    int* h = hist + (size_t)rep * N;
#pragma unroll
    for (int u = 0; u < EPT; ++u) {
        int e = i0 + u;
        if (e < E) atomicAdd(&h[__builtin_nontemporal_load(&col[e])], 1);
    }
#pragma unroll
    for (int u = 0; u < EPT; ++u) {
        int i = i0 + u;
        if (i < total4) {
            f32x4 v = __builtin_nontemporal_load(&((const f32x4*)x)[i]);
            H4 p;
            p.h[0] = (_Float16)v.x; p.h[1] = (_Float16)v.y;
            p.h[2] = (_Float16)v.z; p.h[3] = (_Float16)v.w;
            ((f32x2*)xh)[i] = p.f2;            // reused by layer 0 -> keep cacheable
        }
    }
}

// ---- 2. fused node-side: deg-sum + dinv + exclusive scan + cursor seed ----
__global__ __launch_bounds__(1024) void nodeproc_kernel(
        const int* __restrict__ hist, float* __restrict__ dinv,
        int* __restrict__ start, int* __restrict__ cursor, int N) {
    __shared__ int wsum[16];
    __shared__ int carry_s;
    int tid = threadIdx.x, lane = tid & 63, wid = tid >> 6;
    if (tid == 0) carry_s = 0;
    __syncthreads();
    for (int base = 0; base < N; base += 1024) {
        int i = base + tid;
        int h[NREP];
        int v = 0;
        if (i < N) {
#pragma unroll
            for (int r = 0; r < NREP; ++r) { h[r] = hist[(size_t)r * N + i]; v += h[r]; }
            int d = v < 1 ? 1 : v;
            dinv[i] = rsqrtf((float)d);
        }
        int inc = v;                              // wave-inclusive scan
        for (int off = 1; off < 64; off <<= 1) {
            int t = __shfl_up(inc, off, 64);
            if (lane >= off) inc += t;
        }
        if (lane == 63) wsum[wid] = inc;
        __syncthreads();
        if (wid == 0) {
            int wv = (lane < 16) ? wsum[lane] : 0;
            for (int off = 1; off < 16; off <<= 1) {
                int t = __shfl_up(wv, off, 64);
                if (lane >= off) wv += t;
            }
            if (lane < 16) wsum[lane] = wv;       // inclusive wave totals
        }
        __syncthreads();
        int carry = carry_s;
        int woff = (wid > 0) ? wsum[wid - 1] : 0;
        if (i < N) {
            int st = carry + woff + inc - v;      // exclusive prefix
            start[i] = st;
            int run = st;
#pragma unroll
            for (int r = 0; r < NREP; ++r) { cursor[(size_t)r * N + i] = run; run += h[r]; }
        }
        __syncthreads();
        if (tid == 0) carry_s = carry + wsum[15];
        __syncthreads();
    }
    if (tid == 0) start[N] = carry_s;
}

// ---- 3. bucket scatter: packed 4B records, pre-seeded replicated cursors ----
__global__ void bucket_kernel(const int* __restrict__ row, const int* __restrict__ col,
                              const float* __restrict__ dinv,
                              int* __restrict__ cursor, ERec* __restrict__ edges,
                              int E, int N) {
    int rep = blockIdx.x & (NREP - 1);
    int e0 = (blockIdx.x * blockDim.x + threadIdx.x) * EPT;
    int* cur = cursor + (size_t)rep * N;
    int cs[EPT], rs[EPT], pos[EPT];
    float nm[EPT];
#pragma unroll
    for (int u = 0; u < EPT; ++u) {
        int e = e0 + u;
        if (e < E) {
            cs[u] = __builtin_nontemporal_load(&col[e]);
            rs[u] = __builtin_nontemporal_load(&row[e]);
        }
    }
#pragma unroll
    for (int u = 0; u < EPT; ++u) {
        int e = e0 + u;
        if (e < E) {
            nm[u]  = dinv[rs[u]] * dinv[cs[u]];
            pos[u] = atomicAdd(&cur[cs[u]], 1);
        }
    }
#pragma unroll
    for (int u = 0; u < EPT; ++u) {
        int e = e0 + u;
        if (e < E) {
            HS hs; hs.h = (_Float16)nm[u];
            ERec rec = (uint32_t)rs[u] | ((uint32_t)hs.u << 16);
            edges[pos[u]] = rec;               // reused 8x by layers -> cacheable
        }
    }
}

// ---- 4. one layer: quarter-wave f32x4 gathers + packed-fp16 MAC ----
// Single change this round: cout store is NON-TEMPORAL so dirty lines leave
// the writer XCD's L2 promptly; next layer's cross-XCD reads hit clean L3.
__global__ __launch_bounds__(256) void layer_kernel(
        const _Float16* __restrict__ cin, _Float16* __restrict__ cout,
        const int* __restrict__ start, const ERec* __restrict__ edges, int N) {
    int node = (blockIdx.x * blockDim.x + threadIdx.x) >> 6;
    int lane = threadIdx.x & 63;
    if (node >= N) return;
    int q  = lane >> 4;        // quarter 0..3
    int li = lane & 15;        // lane-in-quarter
    int s = start[node], t = start[node + 1];

    float a[8];
#pragma unroll
    for (int i = 0; i < 8; ++i) a[i] = 0.f;

    for (int base = s; base < t; base += 64) {
        int cnt = t - base; if (cnt > 64) cnt = 64;
        ERec rec = edges[base + (lane < cnt ? lane : cnt - 1)];   // coalesced staging
        int j = 0;
        for (; j + 32 <= cnt; j += 32) {
            h2 hacc[4];
#pragma unroll
            for (int c = 0; c < 4; ++c) hacc[c] = (h2)(_Float16)0.f;
#pragma unroll
            for (int u = 0; u < 8; ++u) {          // 8 edges per quarter
                int idx = j + 4 * u + q;
                uint32_t r_ = (uint32_t)__shfl((int)rec, idx, 64);
                int s_ = (int)(r_ & 0xffffu);
                HS hs; hs.u = (unsigned short)(r_ >> 16);
                h2 n2; n2[0] = hs.h; n2[1] = hs.h;
                H8 v; v.f4 = ((const f32x4*)(cin + (size_t)s_ * F))[li];
#pragma unroll
                for (int c = 0; c < 4; ++c) hacc[c] += n2 * v.p[c];  // v_pk_fma_f16
            }
#pragma unroll
            for (int c = 0; c < 4; ++c) {          // flush to fp32
                a[2 * c]     += (float)hacc[c][0];
                a[2 * c + 1] += (float)hacc[c][1];
            }
        }
        for (; j < cnt; j += 4) {                  // remainder: fp32 path
            int idx = j + q;
            int ic  = idx < cnt ? idx : j;
            uint32_t r_ = (uint32_t)__shfl((int)rec, ic, 64);
            int s_ = (int)(r_ & 0xffffu);
            HS hs; hs.u = (unsigned short)(r_ >> 16);
            float n_ = (float)hs.h;
            if (idx >= cnt) n_ = 0.f;
            H8 v; v.f4 = ((const f32x4*)(cin + (size_t)s_ * F))[li];
#pragma unroll
            for (int i = 0; i < 8; ++i) a[i] += n_ * (float)v.h[i];
        }
    }
    // combine quarters (lanes li, li+16, li+32, li+48 hold same columns)
#pragma unroll
    for (int i = 0; i < 8; ++i) {
        a[i] += __shfl_xor(a[i], 16, 64);
        a[i] += __shfl_xor(a[i], 32, 64);
    }
    if (q == 0) {
        H8 c; c.f4 = ((const f32x4*)(cin + (size_t)node * F))[li];
        H8 o;
#pragma unroll
        for (int i = 0; i < 8; ++i) o.h[i] = (_Float16)((float)c.h[i] - a[i]);
        __builtin_nontemporal_store(o.f4, &((f32x4*)(cout + (size_t)node * F))[li]);
    }
}

// ---- 5. epilogue: update = sum_l tanh(k_l)*cur_l; h = c*upd+(1-c)*x;
//          out = relu(h @ W^T + b) ----
#define TM 32
#define KC 32
__global__ __launch_bounds__(256) void final_kernel(
        const float* __restrict__ x, const _Float16* __restrict__ curh,
        const float* __restrict__ W, const float* __restrict__ bias,
        const float* __restrict__ kv, const float* __restrict__ wt,
        float* __restrict__ out, int N, int L) {
    __shared__ float hs[TM * F];
    __shared__ float Wl[KC * 129];
    int tid  = threadIdx.x;
    int row0 = blockIdx.x * TM;
    float cst  = 1.f / (1.f + __expf(-wt[0]));
    float cst1 = 1.f - cst;
    float t[16];
    for (int l = 0; l < L; ++l) t[l] = tanhf(kv[l]);
    const size_t NF = (size_t)N * F;

    for (int j = tid; j < TM * 32; j += 256) {
        int r = j >> 5, qd = j & 31;
        int gr = row0 + r;
        f32x4 hv = {0.f, 0.f, 0.f, 0.f};
        if (gr < N) {
            f32x4 xv = __builtin_nontemporal_load(&((const f32x4*)(x + (size_t)gr * F))[qd]);
            float sx = 0.f, sy = 0.f, sz = 0.f, sw = 0.f;
            for (int l = 0; l < L; ++l) {
                H4 u;
                u.f2 = __builtin_nontemporal_load(
                    &((const f32x2*)(curh + (size_t)l * NF + (size_t)gr * F))[qd]);
                sx += t[l] * (float)u.h[0]; sy += t[l] * (float)u.h[1];
                sz += t[l] * (float)u.h[2]; sw += t[l] * (float)u.h[3];
            }
            hv.x = cst * sx + cst1 * xv.x;
            hv.y = cst * sy + cst1 * xv.y;
            hv.z = cst * sz + cst1 * xv.z;
            hv.w = cst * sw + cst1 * xv.w;
        }
        ((f32x4*)hs)[j] = hv;
    }

    int c  = tid & 127;
    int rg = tid >> 7;
    float acc[16];
#pragma unroll
    for (int i = 0; i < 16; ++i) acc[i] = 0.f;
    for (int kc = 0; kc < F; kc += KC) {
        __syncthreads();
        for (int j = tid; j < KC * F; j += 256) {
            int c2 = j >> 5, kk = j & 31;
            Wl[kk * 129 + c2] = W[(size_t)c2 * F + kc + kk];
        }
        __syncthreads();
#pragma unroll 8
        for (int kk = 0; kk < KC; ++kk) {
            float w = Wl[kk * 129 + c];
#pragma unroll
            for (int r = 0; r < 16; ++r)
                acc[r] += hs[(rg * 16 + r) * F + kc + kk] * w;
        }
    }
    float bv = bias[c];
#pragma unroll
    for (int r = 0; r < 16; ++r) {
        int gr = row0 + rg * 16 + r;
        if (gr < N) {
            float v = acc[r] + bv;
            out[(size_t)gr * F + c] = v > 0.f ? v : 0.f;
        }
    }
}

extern "C" void kernel_launch(void* const* d_in, const int* in_sizes, int n_in,
                              void* d_out, int out_size, void* d_ws, size_t ws_size,
                              hipStream_t stream) {
    const float* x   = (const float*)d_in[0];
    const int*   ei  = (const int*)d_in[1];
    const float* kv  = (const float*)d_in[2];
    const float* wt  = (const float*)d_in[3];
    const float* W   = (const float*)d_in[4];
    const float* b   = (const float*)d_in[5];
    float* out = (float*)d_out;

    const int E = in_sizes[1] / 2;
    const int N = in_sizes[0] / F;
    const int L = in_sizes[2];
    const int* row = ei;           // edge_index[0]
    const int* col = ei + E;       // edge_index[1]
    const size_t NF = (size_t)N * F;
    const int total4 = (int)(NF / 4);

    size_t off = 0;
    auto alloc = [&](size_t bytes) {
        void* p = (char*)d_ws + off;
        off += (bytes + 255) & ~(size_t)255;
        return p;
    };
    int*      hist   = (int*)alloc((size_t)NREP * N * 4);
    int*      cursor = (int*)alloc((size_t)NREP * N * 4);
    int*      startp = (int*)alloc((size_t)(N + 1) * 4);
    float*    dinv   = (float*)alloc((size_t)N * 4);
    ERec*     edges  = (ERec*)alloc((size_t)E * sizeof(ERec));
    _Float16* xh     = (_Float16*)alloc(NF * 2);
    _Float16* curh   = (_Float16*)alloc((size_t)L * NF * 2);
    (void)ws_size;

    (void)hipMemsetAsync(hist, 0, (size_t)NREP * N * 4, stream);

    const int work = (E > total4 ? E : total4);
    const int nb_edge = (work + 256 * EPT - 1) / (256 * EPT);   // same geometry for bucket
    convdeg_kernel<<<nb_edge, 256, 0, stream>>>(x, xh, total4, col, hist, E, N);
    nodeproc_kernel<<<1, 1024, 0, stream>>>(hist, dinv, startp, cursor, N);
    bucket_kernel<<<nb_edge, 256, 0, stream>>>(row, col, dinv, cursor, edges, E, N);

    for (int l = 0; l < L; ++l) {
        const _Float16* cin = (l == 0) ? xh : curh + (size_t)(l - 1) * NF;
        _Float16* cout = curh + (size_t)l * NF;
        layer_kernel<<<(N * 64 + 255) / 256, 256, 0, stream>>>(cin, cout, startp, edges, N);
    }

    final_kernel<<<(N + TM - 1) / TM, 256, 0, stream>>>(x, curh, W, b, kv, wt, out, N, L);
}